// Round 5
// baseline (418.421 us; speedup 1.0000x reference)
//
#include <hip/hip_runtime.h>

#define B_ 2
#define N_ 192
#define DIM_ 512
#define H_ 8
#define DH_ 64
#define PROJ_ELEMS (B_*H_*N_*DH_)   // 196608
#define W_ELEMS (DIM_*DIM_)         // 262144
#define A_ELEMS (B_*N_*DIM_)        // 196608

typedef __bf16 bf16_t;
typedef __bf16 bf16x4 __attribute__((ext_vector_type(4)));
typedef __bf16 bf16x8 __attribute__((ext_vector_type(8)));
typedef float  f32x16 __attribute__((ext_vector_type(16)));

__device__ __forceinline__ f32x16 mfma32(bf16x8 a, bf16x8 b, f32x16 c) {
    return __builtin_amdgcn_mfma_f32_32x32x16_bf16(a, b, c, 0, 0, 0);
}

union U4 { unsigned int u[4]; bf16x8 v; };

__device__ __forceinline__ unsigned int pack_bf16(float a, float b) {
    unsigned short ua = __builtin_bit_cast(unsigned short, (bf16_t)a);
    unsigned short ub = __builtin_bit_cast(unsigned short, (bf16_t)b);
    return (unsigned int)ua | ((unsigned int)ub << 16);
}
__device__ __forceinline__ float bfbits(unsigned short u) {
    return (float)__builtin_bit_cast(bf16_t, u);
}

// ---------------- f32 -> bf16 conversion ----------------
struct CArgs {
    const float* src[8];
    bf16_t* dst[8];
    int n[8];
};
__global__ __launch_bounds__(256) void cvt_kernel(CArgs a) {
    const int s = blockIdx.y;
    const int i = (blockIdx.x * 256 + threadIdx.x) * 4;
    if (i < a.n[s]) {
        float4 v = *(const float4*)(a.src[s] + i);
        bf16x4 o;
        o[0] = (bf16_t)v.x; o[1] = (bf16_t)v.y; o[2] = (bf16_t)v.z; o[3] = (bf16_t)v.w;
        *(bf16x4*)(a.dst[s] + i) = o;
    }
}

// ---------------- unified 64x64-tile bf16 GEMM ----------------
struct GArgs {
    const bf16_t* A[4];
    const bf16_t* Bm[4];
    const float* bias[4];
    float scale[4];
};

template<int MODE>
__global__ __launch_bounds__(256) void gemm64_kernel(GArgs g, void* outp) {
    const int mat = blockIdx.y;
    const bf16_t* __restrict__ A  = g.A[mat];
    const bf16_t* __restrict__ Bm = g.Bm[mat];

    const int rt = blockIdx.x >> 3, ct = blockIdx.x & 7;
    const int r0 = rt * 64, c0 = ct * 64;
    const int tid = threadIdx.x, wid = tid >> 6, lane = tid & 63;
    const int lo = lane & 31, hi = lane >> 5;
    const int wr = wid >> 1, wc = wid & 1;

    __shared__ __attribute__((aligned(16))) bf16_t As[64 * 64];
    __shared__ __attribute__((aligned(16))) bf16_t Bs[64 * 64];

    f32x16 acc = {};
    for (int k0 = 0; k0 < DIM_; k0 += 64) {
        #pragma unroll
        for (int cch = 0; cch < 2; ++cch) {
            const int d = wid * 2048 + cch * 1024 + lane * 16;
            const int r = d >> 7;
            const int off = (d ^ ((r & 7) << 4)) & 127;
            const char* srcA = (const char*)A + (size_t)(r0 + r) * (DIM_ * 2) + k0 * 2 + off;
            const char* srcB = (const char*)Bm + (size_t)(c0 + r) * (DIM_ * 2) + k0 * 2 + off;
            __builtin_amdgcn_global_load_lds(
                (const __attribute__((address_space(1))) void*)srcA,
                (__attribute__((address_space(3))) void*)((char*)As + wid * 2048 + cch * 1024),
                16, 0, 0);
            __builtin_amdgcn_global_load_lds(
                (const __attribute__((address_space(1))) void*)srcB,
                (__attribute__((address_space(3))) void*)((char*)Bs + wid * 2048 + cch * 1024),
                16, 0, 0);
        }
        __syncthreads();
        const int rowA = wr * 32 + lo, rowB = wc * 32 + lo;
        #pragma unroll
        for (int s = 0; s < 4; ++s) {
            const int ka = (rowA * 128 + s * 32 + hi * 16) ^ ((rowA & 7) << 4);
            const int kb = (rowB * 128 + s * 32 + hi * 16) ^ ((rowB & 7) << 4);
            bf16x8 af = *(const bf16x8*)((const char*)As + ka);
            bf16x8 bf = *(const bf16x8*)((const char*)Bs + kb);
            acc = mfma32(af, bf, acc);
        }
        __syncthreads();
    }

    const int c = c0 + wc * 32 + lo;
    const float bv = g.bias[mat][c];
    if (MODE == 0) {
        const float sc = g.scale[mat];
        const int h = c >> 6, dd = c & 63;
        bf16_t* out = (bf16_t*)outp + (size_t)mat * PROJ_ELEMS;
        #pragma unroll
        for (int r = 0; r < 16; ++r) {
            int row = r0 + wr * 32 + (r & 3) + 8 * (r >> 2) + 4 * hi;
            int bb = (row >= N_) ? 1 : 0;
            int n = row - bb * N_;
            out[(((size_t)(bb * H_ + h)) * N_ + n) * DH_ + dd] = (bf16_t)((acc[r] + bv) * sc);
        }
    } else {
        float* out = (float*)outp;
        #pragma unroll
        for (int r = 0; r < 16; ++r) {
            int row = r0 + wr * 32 + (r & 3) + 8 * (r >> 2) + 4 * hi;
            out[(size_t)row * DIM_ + c] = acc[r] + bv;
        }
    }
}

// ---------------- fused third-order attention ----------------
// grid (48, 8) x 512 thr: 2 independent bh-groups of 4 waves per block.
// Group g = wid>>2 handles bh = blockIdx.y*2 + g; wave-in-group = wid&3 owns
// i = blockIdx.x*4 + (wid&3). Per-wave body identical to the round-3 passing
// kernel, except L fragments are read from global (L2-hot) instead of LDS.
// LDS = 2 x V^T (64x200) = 51.2KB -> 3 blocks/CU = 24 waves/CU (6/SIMD).
__global__ __launch_bounds__(512, 6) void attn_kernel(
    const bf16_t* __restrict__ Qg, const bf16_t* __restrict__ Kg,
    const bf16_t* __restrict__ Lg, const bf16_t* __restrict__ Vg,
    bf16_t* __restrict__ Xout)
{
    __shared__ __attribute__((aligned(16))) bf16_t VTlds2[2][64 * 200];  // [g][d][k] pitch 200

    const int tid = threadIdx.x, wid = tid >> 6, lane = tid & 63;
    const int lo = lane & 31, hi = lane >> 5;

    // ---- stage V^T for both groups ----
    for (int idx = tid; idx < 3072; idx += 512) {
        int g = idx / 1536, i2 = idx - g * 1536;
        int dc = i2 / 192, j = i2 - dc * 192;
        const size_t vbase = (size_t)(blockIdx.y * 2 + g) * (N_ * DH_);
        bf16x8 v = *(const bf16x8*)(Vg + vbase + (size_t)j * 64 + dc * 8);
        #pragma unroll
        for (int u = 0; u < 8; ++u)
            VTlds2[g][(dc * 8 + u) * 200 + j] = v[u];
    }
    __syncthreads();

    const int grp = wid >> 2;
    const int bh = blockIdx.y * 2 + grp;
    const size_t base = (size_t)bh * (N_ * DH_);
    const bf16_t* VTlds = VTlds2[grp];

    const int i = blockIdx.x * 4 + (wid & 3);
    const bf16_t* qp = Qg + base + (size_t)i * 64;
    bf16x8 qb[4];
    #pragma unroll
    for (int s = 0; s < 4; ++s) qb[s] = *(const bf16x8*)(qp + s * 16 + hi * 8);

    float xacc0 = 0.f, xacc1 = 0.f;
    float Zp[4] = {0.f, 0.f, 0.f, 0.f};

    for (int jb = 0; jb < 6; ++jb) {
        // B-frag for S^T: (q .* K)[j = jb*32+lo][d], from global (L2-hot)
        bf16x8 bq[4];
        const bf16_t* kp = Kg + base + (size_t)(jb * 32 + lo) * 64;
        #pragma unroll
        for (int s = 0; s < 4; ++s) {
            bf16x8 kv = *(const bf16x8*)(kp + s * 16 + hi * 8);
            bf16x8 t;
            #pragma unroll
            for (int u = 0; u < 8; ++u) t[u] = (bf16_t)((float)kv[u] * (float)qb[s][u]);
            bq[s] = t;
        }

        f32x16 Tc0 = {}, Tc1 = {};
        #pragma unroll
        for (int kh = 0; kh < 2; ++kh) {
            // S^T[k = kh*96 + kt*32 + rows][j = jb*32 + lo], K-dim d = 64
            f32x16 Sc[3];
            #pragma unroll
            for (int kt = 0; kt < 3; ++kt) {
                f32x16 a = {};
                const bf16_t* lrow = Lg + base + (size_t)(kh * 96 + kt * 32 + lo) * 64;
                #pragma unroll
                for (int s = 0; s < 4; ++s) {
                    bf16x8 lf = *(const bf16x8*)(lrow + s * 16 + hi * 8);
                    a = mfma32(lf, bq[s], a);
                }
                Sc[kt] = a;
            }
            #pragma unroll
            for (int kt = 0; kt < 3; ++kt) {
                float e[16];
                #pragma unroll
                for (int r = 0; r < 16; ++r) {
                    e[r] = __builtin_amdgcn_exp2f(Sc[kt][r]);
                    Zp[r & 3] += e[r];
                }
                #pragma unroll
                for (int sg = 0; sg < 2; ++sg) {
                    unsigned int x0 = pack_bf16(e[8*sg+0], e[8*sg+1]);
                    unsigned int x1 = pack_bf16(e[8*sg+2], e[8*sg+3]);
                    unsigned int y0 = pack_bf16(e[8*sg+4], e[8*sg+5]);
                    unsigned int y1 = pack_bf16(e[8*sg+6], e[8*sg+7]);
                    asm volatile("v_permlane32_swap_b32 %0, %1\n\t"
                                 "v_permlane32_swap_b32 %2, %3"
                                 : "+v"(x0), "+v"(y0), "+v"(x1), "+v"(y1));
                    U4 uf; uf.u[0] = x0; uf.u[1] = x1; uf.u[2] = y0; uf.u[3] = y1;
                    const int tg = kh * 6 + kt * 2 + sg;     // k-slice 0..11
                    bf16x8 vf0 = *(const bf16x8*)&VTlds[(0 * 32 + lo) * 200 + tg * 16 + hi * 8];
                    Tc0 = mfma32(uf.v, vf0, Tc0);
                    bf16x8 vf1 = *(const bf16x8*)&VTlds[(1 * 32 + lo) * 200 + tg * 16 + hi * 8];
                    Tc1 = mfma32(uf.v, vf1, Tc1);
                }
            }
        }
        // x[d] += v[j,d] * T[j,d] over this strip's 32 j
        #pragma unroll
        for (int m = 0; m < 4; ++m) {
            const int jj = jb * 32 + m * 8 + 4 * hi;
            ushort4 v0 = *(const ushort4*)&VTlds[(0 * 32 + lo) * 200 + jj];
            ushort4 v1 = *(const ushort4*)&VTlds[(1 * 32 + lo) * 200 + jj];
            xacc0 += Tc0[m*4+0]*bfbits(v0.x) + Tc0[m*4+1]*bfbits(v0.y)
                   + Tc0[m*4+2]*bfbits(v0.z) + Tc0[m*4+3]*bfbits(v0.w);
            xacc1 += Tc1[m*4+0]*bfbits(v1.x) + Tc1[m*4+1]*bfbits(v1.y)
                   + Tc1[m*4+2]*bfbits(v1.z) + Tc1[m*4+3]*bfbits(v1.w);
        }
    }

    float Z = (Zp[0] + Zp[1]) + (Zp[2] + Zp[3]);
    Z += __shfl_xor(Z, 1);
    Z += __shfl_xor(Z, 2);
    Z += __shfl_xor(Z, 4);
    Z += __shfl_xor(Z, 8);
    Z += __shfl_xor(Z, 16);
    Z += __shfl_xor(Z, 32);
    xacc0 += __shfl_xor(xacc0, 32);
    xacc1 += __shfl_xor(xacc1, 32);
    const float invZ = 1.0f / Z;

    if (hi == 0) {
        const int b = bh >> 3, h = bh & 7;
        bf16_t* op = Xout + ((size_t)(b * N_ + i) * DIM_) + h * 64;
        op[lo]      = (bf16_t)(xacc0 * invZ);
        op[32 + lo] = (bf16_t)(xacc1 * invZ);
    }
}

extern "C" void kernel_launch(void* const* d_in, const int* in_sizes, int n_in,
                              void* d_out, int out_size, void* d_ws, size_t ws_size,
                              hipStream_t stream) {
    (void)in_sizes; (void)n_in; (void)out_size; (void)ws_size;
    const float* queries = (const float*)d_in[0];
    const float* keys    = (const float*)d_in[1];
    const float* values  = (const float*)d_in[2];
    const float* Wq = (const float*)d_in[3];
    const float* bq = (const float*)d_in[4];
    const float* Wk = (const float*)d_in[5];
    const float* bk = (const float*)d_in[6];
    const float* Wl = (const float*)d_in[7];
    const float* bl = (const float*)d_in[8];
    const float* Wv = (const float*)d_in[9];
    const float* bv = (const float*)d_in[10];
    const float* Wp = (const float*)d_in[11];
    const float* bp = (const float*)d_in[12];

    bf16_t* Abf = (bf16_t*)d_ws;
    bf16_t* Wbf = Abf + 3 * (size_t)A_ELEMS;
    bf16_t* Pw  = Wbf + 5 * (size_t)W_ELEMS;
    bf16_t* Xw  = Pw  + 4 * (size_t)PROJ_ELEMS;

    CArgs ca;
    ca.src[0] = queries; ca.dst[0] = Abf;               ca.n[0] = A_ELEMS;
    ca.src[1] = keys;    ca.dst[1] = Abf + A_ELEMS;     ca.n[1] = A_ELEMS;
    ca.src[2] = values;  ca.dst[2] = Abf + 2*A_ELEMS;   ca.n[2] = A_ELEMS;
    ca.src[3] = Wq;      ca.dst[3] = Wbf;               ca.n[3] = W_ELEMS;
    ca.src[4] = Wk;      ca.dst[4] = Wbf + W_ELEMS;     ca.n[4] = W_ELEMS;
    ca.src[5] = Wl;      ca.dst[5] = Wbf + 2*W_ELEMS;   ca.n[5] = W_ELEMS;
    ca.src[6] = Wv;      ca.dst[6] = Wbf + 3*W_ELEMS;   ca.n[6] = W_ELEMS;
    ca.src[7] = Wp;      ca.dst[7] = Wbf + 4*W_ELEMS;   ca.n[7] = W_ELEMS;
    cvt_kernel<<<dim3(256, 8), 256, 0, stream>>>(ca);

    GArgs pa;
    pa.A[0] = Abf;             pa.Bm[0] = Wbf;             pa.bias[0] = bq; pa.scale[0] = 0.125f * 1.44269504f;
    pa.A[1] = Abf + A_ELEMS;   pa.Bm[1] = Wbf + W_ELEMS;   pa.bias[1] = bk; pa.scale[1] = 1.0f;
    pa.A[2] = Abf + A_ELEMS;   pa.Bm[2] = Wbf + 2*W_ELEMS; pa.bias[2] = bl; pa.scale[2] = 1.0f;
    pa.A[3] = Abf + 2*A_ELEMS; pa.Bm[3] = Wbf + 3*W_ELEMS; pa.bias[3] = bv; pa.scale[3] = 1.0f;
    gemm64_kernel<0><<<dim3(48, 4), 256, 0, stream>>>(pa, (void*)Pw);

    attn_kernel<<<dim3(48, 8), 512, 0, stream>>>(
        Pw, Pw + PROJ_ELEMS, Pw + 2 * (size_t)PROJ_ELEMS, Pw + 3 * (size_t)PROJ_ELEMS, Xw);

    GArgs fa;
    fa.A[0] = Xw; fa.Bm[0] = Wbf + 4*W_ELEMS; fa.bias[0] = bp; fa.scale[0] = 1.0f;
    fa.A[1] = fa.A[0]; fa.Bm[1] = fa.Bm[0]; fa.bias[1] = fa.bias[0]; fa.scale[1] = 1.0f;
    fa.A[2] = fa.A[0]; fa.Bm[2] = fa.Bm[0]; fa.bias[2] = fa.bias[0]; fa.scale[2] = 1.0f;
    fa.A[3] = fa.A[0]; fa.Bm[3] = fa.Bm[0]; fa.bias[3] = fa.bias[0]; fa.scale[3] = 1.0f;
    gemm64_kernel<1><<<dim3(48, 1), 256, 0, stream>>>(fa, d_out);
}

// Round 6
// 208.693 us; speedup vs baseline: 2.0050x; 2.0050x over previous
//
#include <hip/hip_runtime.h>

#define B_ 2
#define N_ 192
#define DIM_ 512
#define H_ 8
#define DH_ 64
#define PROJ_ELEMS (B_*H_*N_*DH_)   // 196608
#define W_ELEMS (DIM_*DIM_)         // 262144
#define A_ELEMS (B_*N_*DIM_)        // 196608

typedef __bf16 bf16_t;
typedef __bf16 bf16x4 __attribute__((ext_vector_type(4)));
typedef __bf16 bf16x8 __attribute__((ext_vector_type(8)));
typedef float  f32x16 __attribute__((ext_vector_type(16)));

__device__ __forceinline__ f32x16 mfma32(bf16x8 a, bf16x8 b, f32x16 c) {
    return __builtin_amdgcn_mfma_f32_32x32x16_bf16(a, b, c, 0, 0, 0);
}

union U4 { unsigned int u[4]; bf16x8 v; };

__device__ __forceinline__ unsigned int pack_bf16(float a, float b) {
    unsigned short ua = __builtin_bit_cast(unsigned short, (bf16_t)a);
    unsigned short ub = __builtin_bit_cast(unsigned short, (bf16_t)b);
    return (unsigned int)ua | ((unsigned int)ub << 16);
}
__device__ __forceinline__ float bfbits(unsigned short u) {
    return (float)__builtin_bit_cast(bf16_t, u);
}

// ---------------- f32 -> bf16 conversion ----------------
struct CArgs {
    const float* src[8];
    bf16_t* dst[8];
    int n[8];
};
__global__ __launch_bounds__(256) void cvt_kernel(CArgs a) {
    const int s = blockIdx.y;
    const int i = (blockIdx.x * 256 + threadIdx.x) * 4;
    if (i < a.n[s]) {
        float4 v = *(const float4*)(a.src[s] + i);
        bf16x4 o;
        o[0] = (bf16_t)v.x; o[1] = (bf16_t)v.y; o[2] = (bf16_t)v.z; o[3] = (bf16_t)v.w;
        *(bf16x4*)(a.dst[s] + i) = o;
    }
}

// ---------------- unified 64x64-tile bf16 GEMM ----------------
struct GArgs {
    const bf16_t* A[4];
    const bf16_t* Bm[4];
    const float* bias[4];
    float scale[4];
};

template<int MODE>
__global__ __launch_bounds__(256) void gemm64_kernel(GArgs g, void* outp) {
    const int mat = blockIdx.y;
    const bf16_t* __restrict__ A  = g.A[mat];
    const bf16_t* __restrict__ Bm = g.Bm[mat];

    const int rt = blockIdx.x >> 3, ct = blockIdx.x & 7;
    const int r0 = rt * 64, c0 = ct * 64;
    const int tid = threadIdx.x, wid = tid >> 6, lane = tid & 63;
    const int lo = lane & 31, hi = lane >> 5;
    const int wr = wid >> 1, wc = wid & 1;

    __shared__ __attribute__((aligned(16))) bf16_t As[64 * 64];
    __shared__ __attribute__((aligned(16))) bf16_t Bs[64 * 64];

    f32x16 acc = {};
    for (int k0 = 0; k0 < DIM_; k0 += 64) {
        #pragma unroll
        for (int cch = 0; cch < 2; ++cch) {
            const int d = wid * 2048 + cch * 1024 + lane * 16;
            const int r = d >> 7;
            const int off = (d ^ ((r & 7) << 4)) & 127;
            const char* srcA = (const char*)A + (size_t)(r0 + r) * (DIM_ * 2) + k0 * 2 + off;
            const char* srcB = (const char*)Bm + (size_t)(c0 + r) * (DIM_ * 2) + k0 * 2 + off;
            __builtin_amdgcn_global_load_lds(
                (const __attribute__((address_space(1))) void*)srcA,
                (__attribute__((address_space(3))) void*)((char*)As + wid * 2048 + cch * 1024),
                16, 0, 0);
            __builtin_amdgcn_global_load_lds(
                (const __attribute__((address_space(1))) void*)srcB,
                (__attribute__((address_space(3))) void*)((char*)Bs + wid * 2048 + cch * 1024),
                16, 0, 0);
        }
        __syncthreads();
        const int rowA = wr * 32 + lo, rowB = wc * 32 + lo;
        #pragma unroll
        for (int s = 0; s < 4; ++s) {
            const int ka = (rowA * 128 + s * 32 + hi * 16) ^ ((rowA & 7) << 4);
            const int kb = (rowB * 128 + s * 32 + hi * 16) ^ ((rowB & 7) << 4);
            bf16x8 af = *(const bf16x8*)((const char*)As + ka);
            bf16x8 bf = *(const bf16x8*)((const char*)Bs + kb);
            acc = mfma32(af, bf, acc);
        }
        __syncthreads();
    }

    const int c = c0 + wc * 32 + lo;
    const float bv = g.bias[mat][c];
    if (MODE == 0) {
        const float sc = g.scale[mat];
        const int h = c >> 6, dd = c & 63;
        bf16_t* out = (bf16_t*)outp + (size_t)mat * PROJ_ELEMS;
        #pragma unroll
        for (int r = 0; r < 16; ++r) {
            int row = r0 + wr * 32 + (r & 3) + 8 * (r >> 2) + 4 * hi;
            int bb = (row >= N_) ? 1 : 0;
            int n = row - bb * N_;
            out[(((size_t)(bb * H_ + h)) * N_ + n) * DH_ + dd] = (bf16_t)((acc[r] + bv) * sc);
        }
    } else {
        float* out = (float*)outp;
        #pragma unroll
        for (int r = 0; r < 16; ++r) {
            int row = r0 + wr * 32 + (r & 3) + 8 * (r >> 2) + 4 * hi;
            out[(size_t)row * DIM_ + c] = acc[r] + bv;
        }
    }
}

// ---------------- fused third-order attention ----------------
// grid (48, 8) x 512 thr: 2 independent bh-groups of 4 waves per block.
// Group g = wid>>2 handles bh = blockIdx.y*2 + g; wave-in-group = wid&3 owns
// i = blockIdx.x*4 + (wid&3). Per-wave body identical to the round-3 passing
// kernel, except L fragments are read from global (L2-hot) instead of LDS.
// LDS = 2 x V^T (64x200) = 51.2KB -> 3 blocks/CU LDS-wise; VGPR decides waves.
// NOTE round-5 lesson: __launch_bounds__(512,6) (cap~85 VGPR) caused a spill
// catastrophe (VGPR_Count 40, 608MB scratch writes, 336us). Bound relaxed to
// (512,4): cap 128 VGPR >= natural allocation -> no spills.
__global__ __launch_bounds__(512, 4) void attn_kernel(
    const bf16_t* __restrict__ Qg, const bf16_t* __restrict__ Kg,
    const bf16_t* __restrict__ Lg, const bf16_t* __restrict__ Vg,
    bf16_t* __restrict__ Xout)
{
    __shared__ __attribute__((aligned(16))) bf16_t VTlds2[2][64 * 200];  // [g][d][k] pitch 200

    const int tid = threadIdx.x, wid = tid >> 6, lane = tid & 63;
    const int lo = lane & 31, hi = lane >> 5;

    // ---- stage V^T for both groups ----
    for (int idx = tid; idx < 3072; idx += 512) {
        int g = idx / 1536, i2 = idx - g * 1536;
        int dc = i2 / 192, j = i2 - dc * 192;
        const size_t vbase = (size_t)(blockIdx.y * 2 + g) * (N_ * DH_);
        bf16x8 v = *(const bf16x8*)(Vg + vbase + (size_t)j * 64 + dc * 8);
        #pragma unroll
        for (int u = 0; u < 8; ++u)
            VTlds2[g][(dc * 8 + u) * 200 + j] = v[u];
    }
    __syncthreads();

    const int grp = wid >> 2;
    const int bh = blockIdx.y * 2 + grp;
    const size_t base = (size_t)bh * (N_ * DH_);
    const bf16_t* VTlds = VTlds2[grp];

    const int i = blockIdx.x * 4 + (wid & 3);
    const bf16_t* qp = Qg + base + (size_t)i * 64;
    bf16x8 qb[4];
    #pragma unroll
    for (int s = 0; s < 4; ++s) qb[s] = *(const bf16x8*)(qp + s * 16 + hi * 8);

    float xacc0 = 0.f, xacc1 = 0.f;
    float Zp[4] = {0.f, 0.f, 0.f, 0.f};

    for (int jb = 0; jb < 6; ++jb) {
        // B-frag for S^T: (q .* K)[j = jb*32+lo][d], from global (L2-hot)
        bf16x8 bq[4];
        const bf16_t* kp = Kg + base + (size_t)(jb * 32 + lo) * 64;
        #pragma unroll
        for (int s = 0; s < 4; ++s) {
            bf16x8 kv = *(const bf16x8*)(kp + s * 16 + hi * 8);
            bf16x8 t;
            #pragma unroll
            for (int u = 0; u < 8; ++u) t[u] = (bf16_t)((float)kv[u] * (float)qb[s][u]);
            bq[s] = t;
        }

        f32x16 Tc0 = {}, Tc1 = {};
        #pragma unroll
        for (int kh = 0; kh < 2; ++kh) {
            // S^T[k = kh*96 + kt*32 + rows][j = jb*32 + lo], K-dim d = 64
            f32x16 Sc[3];
            #pragma unroll
            for (int kt = 0; kt < 3; ++kt) {
                f32x16 a = {};
                const bf16_t* lrow = Lg + base + (size_t)(kh * 96 + kt * 32 + lo) * 64;
                #pragma unroll
                for (int s = 0; s < 4; ++s) {
                    bf16x8 lf = *(const bf16x8*)(lrow + s * 16 + hi * 8);
                    a = mfma32(lf, bq[s], a);
                }
                Sc[kt] = a;
            }
            #pragma unroll
            for (int kt = 0; kt < 3; ++kt) {
                float e[16];
                #pragma unroll
                for (int r = 0; r < 16; ++r) {
                    e[r] = __builtin_amdgcn_exp2f(Sc[kt][r]);
                    Zp[r & 3] += e[r];
                }
                #pragma unroll
                for (int sg = 0; sg < 2; ++sg) {
                    unsigned int x0 = pack_bf16(e[8*sg+0], e[8*sg+1]);
                    unsigned int x1 = pack_bf16(e[8*sg+2], e[8*sg+3]);
                    unsigned int y0 = pack_bf16(e[8*sg+4], e[8*sg+5]);
                    unsigned int y1 = pack_bf16(e[8*sg+6], e[8*sg+7]);
                    asm volatile("v_permlane32_swap_b32 %0, %1\n\t"
                                 "v_permlane32_swap_b32 %2, %3"
                                 : "+v"(x0), "+v"(y0), "+v"(x1), "+v"(y1));
                    U4 uf; uf.u[0] = x0; uf.u[1] = x1; uf.u[2] = y0; uf.u[3] = y1;
                    const int tg = kh * 6 + kt * 2 + sg;     // k-slice 0..11
                    bf16x8 vf0 = *(const bf16x8*)&VTlds[(0 * 32 + lo) * 200 + tg * 16 + hi * 8];
                    Tc0 = mfma32(uf.v, vf0, Tc0);
                    bf16x8 vf1 = *(const bf16x8*)&VTlds[(1 * 32 + lo) * 200 + tg * 16 + hi * 8];
                    Tc1 = mfma32(uf.v, vf1, Tc1);
                }
            }
        }
        // x[d] += v[j,d] * T[j,d] over this strip's 32 j
        #pragma unroll
        for (int m = 0; m < 4; ++m) {
            const int jj = jb * 32 + m * 8 + 4 * hi;
            ushort4 v0 = *(const ushort4*)&VTlds[(0 * 32 + lo) * 200 + jj];
            ushort4 v1 = *(const ushort4*)&VTlds[(1 * 32 + lo) * 200 + jj];
            xacc0 += Tc0[m*4+0]*bfbits(v0.x) + Tc0[m*4+1]*bfbits(v0.y)
                   + Tc0[m*4+2]*bfbits(v0.z) + Tc0[m*4+3]*bfbits(v0.w);
            xacc1 += Tc1[m*4+0]*bfbits(v1.x) + Tc1[m*4+1]*bfbits(v1.y)
                   + Tc1[m*4+2]*bfbits(v1.z) + Tc1[m*4+3]*bfbits(v1.w);
        }
    }

    float Z = (Zp[0] + Zp[1]) + (Zp[2] + Zp[3]);
    Z += __shfl_xor(Z, 1);
    Z += __shfl_xor(Z, 2);
    Z += __shfl_xor(Z, 4);
    Z += __shfl_xor(Z, 8);
    Z += __shfl_xor(Z, 16);
    Z += __shfl_xor(Z, 32);
    xacc0 += __shfl_xor(xacc0, 32);
    xacc1 += __shfl_xor(xacc1, 32);
    const float invZ = 1.0f / Z;

    if (hi == 0) {
        const int b = bh >> 3, h = bh & 7;
        bf16_t* op = Xout + ((size_t)(b * N_ + i) * DIM_) + h * 64;
        op[lo]      = (bf16_t)(xacc0 * invZ);
        op[32 + lo] = (bf16_t)(xacc1 * invZ);
    }
}

extern "C" void kernel_launch(void* const* d_in, const int* in_sizes, int n_in,
                              void* d_out, int out_size, void* d_ws, size_t ws_size,
                              hipStream_t stream) {
    (void)in_sizes; (void)n_in; (void)out_size; (void)ws_size;
    const float* queries = (const float*)d_in[0];
    const float* keys    = (const float*)d_in[1];
    const float* values  = (const float*)d_in[2];
    const float* Wq = (const float*)d_in[3];
    const float* bq = (const float*)d_in[4];
    const float* Wk = (const float*)d_in[5];
    const float* bk = (const float*)d_in[6];
    const float* Wl = (const float*)d_in[7];
    const float* bl = (const float*)d_in[8];
    const float* Wv = (const float*)d_in[9];
    const float* bv = (const float*)d_in[10];
    const float* Wp = (const float*)d_in[11];
    const float* bp = (const float*)d_in[12];

    bf16_t* Abf = (bf16_t*)d_ws;
    bf16_t* Wbf = Abf + 3 * (size_t)A_ELEMS;
    bf16_t* Pw  = Wbf + 5 * (size_t)W_ELEMS;
    bf16_t* Xw  = Pw  + 4 * (size_t)PROJ_ELEMS;

    CArgs ca;
    ca.src[0] = queries; ca.dst[0] = Abf;               ca.n[0] = A_ELEMS;
    ca.src[1] = keys;    ca.dst[1] = Abf + A_ELEMS;     ca.n[1] = A_ELEMS;
    ca.src[2] = values;  ca.dst[2] = Abf + 2*A_ELEMS;   ca.n[2] = A_ELEMS;
    ca.src[3] = Wq;      ca.dst[3] = Wbf;               ca.n[3] = W_ELEMS;
    ca.src[4] = Wk;      ca.dst[4] = Wbf + W_ELEMS;     ca.n[4] = W_ELEMS;
    ca.src[5] = Wl;      ca.dst[5] = Wbf + 2*W_ELEMS;   ca.n[5] = W_ELEMS;
    ca.src[6] = Wv;      ca.dst[6] = Wbf + 3*W_ELEMS;   ca.n[6] = W_ELEMS;
    ca.src[7] = Wp;      ca.dst[7] = Wbf + 4*W_ELEMS;   ca.n[7] = W_ELEMS;
    cvt_kernel<<<dim3(256, 8), 256, 0, stream>>>(ca);

    GArgs pa;
    pa.A[0] = Abf;             pa.Bm[0] = Wbf;             pa.bias[0] = bq; pa.scale[0] = 0.125f * 1.44269504f;
    pa.A[1] = Abf + A_ELEMS;   pa.Bm[1] = Wbf + W_ELEMS;   pa.bias[1] = bk; pa.scale[1] = 1.0f;
    pa.A[2] = Abf + A_ELEMS;   pa.Bm[2] = Wbf + 2*W_ELEMS; pa.bias[2] = bl; pa.scale[2] = 1.0f;
    pa.A[3] = Abf + 2*A_ELEMS; pa.Bm[3] = Wbf + 3*W_ELEMS; pa.bias[3] = bv; pa.scale[3] = 1.0f;
    gemm64_kernel<0><<<dim3(48, 4), 256, 0, stream>>>(pa, (void*)Pw);

    attn_kernel<<<dim3(48, 8), 512, 0, stream>>>(
        Pw, Pw + PROJ_ELEMS, Pw + 2 * (size_t)PROJ_ELEMS, Pw + 3 * (size_t)PROJ_ELEMS, Xw);

    GArgs fa;
    fa.A[0] = Xw; fa.Bm[0] = Wbf + 4*W_ELEMS; fa.bias[0] = bp; fa.scale[0] = 1.0f;
    fa.A[1] = fa.A[0]; fa.Bm[1] = fa.Bm[0]; fa.bias[1] = fa.bias[0]; fa.scale[1] = 1.0f;
    fa.A[2] = fa.A[0]; fa.Bm[2] = fa.Bm[0]; fa.bias[2] = fa.bias[0]; fa.scale[2] = 1.0f;
    fa.A[3] = fa.A[0]; fa.Bm[3] = fa.Bm[0]; fa.bias[3] = fa.bias[0]; fa.scale[3] = 1.0f;
    gemm64_kernel<1><<<dim3(48, 1), 256, 0, stream>>>(fa, d_out);
}

// Round 7
// 164.520 us; speedup vs baseline: 2.5433x; 1.2685x over previous
//
#include <hip/hip_runtime.h>

#define B_ 2
#define N_ 192
#define DIM_ 512
#define H_ 8
#define DH_ 64
#define PROJ_ELEMS (B_*H_*N_*DH_)   // 196608
#define W_ELEMS (DIM_*DIM_)         // 262144
#define A_ELEMS (B_*N_*DIM_)        // 196608

typedef __bf16 bf16_t;
typedef __bf16 bf16x4 __attribute__((ext_vector_type(4)));
typedef __bf16 bf16x8 __attribute__((ext_vector_type(8)));
typedef float  f32x16 __attribute__((ext_vector_type(16)));

__device__ __forceinline__ f32x16 mfma32(bf16x8 a, bf16x8 b, f32x16 c) {
    return __builtin_amdgcn_mfma_f32_32x32x16_bf16(a, b, c, 0, 0, 0);
}

union U4 { unsigned int u[4]; bf16x8 v; };

__device__ __forceinline__ unsigned int pack_bf16(float a, float b) {
    unsigned short ua = __builtin_bit_cast(unsigned short, (bf16_t)a);
    unsigned short ub = __builtin_bit_cast(unsigned short, (bf16_t)b);
    return (unsigned int)ua | ((unsigned int)ub << 16);
}
__device__ __forceinline__ float bfbits(unsigned short u) {
    return (float)__builtin_bit_cast(bf16_t, u);
}

// ---------------- f32 -> bf16 conversion ----------------
struct CArgs {
    const float* src[8];
    bf16_t* dst[8];
    int n[8];
};
__global__ __launch_bounds__(256) void cvt_kernel(CArgs a) {
    const int s = blockIdx.y;
    const int i = (blockIdx.x * 256 + threadIdx.x) * 4;
    if (i < a.n[s]) {
        float4 v = *(const float4*)(a.src[s] + i);
        bf16x4 o;
        o[0] = (bf16_t)v.x; o[1] = (bf16_t)v.y; o[2] = (bf16_t)v.z; o[3] = (bf16_t)v.w;
        *(bf16x4*)(a.dst[s] + i) = o;
    }
}

// ---------------- unified 64x64-tile bf16 GEMM ----------------
struct GArgs {
    const bf16_t* A[4];
    const bf16_t* Bm[4];
    const float* bias[4];
    float scale[4];
};

template<int MODE>
__global__ __launch_bounds__(256) void gemm64_kernel(GArgs g, void* outp) {
    const int mat = blockIdx.y;
    const bf16_t* __restrict__ A  = g.A[mat];
    const bf16_t* __restrict__ Bm = g.Bm[mat];

    const int rt = blockIdx.x >> 3, ct = blockIdx.x & 7;
    const int r0 = rt * 64, c0 = ct * 64;
    const int tid = threadIdx.x, wid = tid >> 6, lane = tid & 63;
    const int lo = lane & 31, hi = lane >> 5;
    const int wr = wid >> 1, wc = wid & 1;

    __shared__ __attribute__((aligned(16))) bf16_t As[64 * 64];
    __shared__ __attribute__((aligned(16))) bf16_t Bs[64 * 64];

    f32x16 acc = {};
    for (int k0 = 0; k0 < DIM_; k0 += 64) {
        #pragma unroll
        for (int cch = 0; cch < 2; ++cch) {
            const int d = wid * 2048 + cch * 1024 + lane * 16;
            const int r = d >> 7;
            const int off = (d ^ ((r & 7) << 4)) & 127;
            const char* srcA = (const char*)A + (size_t)(r0 + r) * (DIM_ * 2) + k0 * 2 + off;
            const char* srcB = (const char*)Bm + (size_t)(c0 + r) * (DIM_ * 2) + k0 * 2 + off;
            __builtin_amdgcn_global_load_lds(
                (const __attribute__((address_space(1))) void*)srcA,
                (__attribute__((address_space(3))) void*)((char*)As + wid * 2048 + cch * 1024),
                16, 0, 0);
            __builtin_amdgcn_global_load_lds(
                (const __attribute__((address_space(1))) void*)srcB,
                (__attribute__((address_space(3))) void*)((char*)Bs + wid * 2048 + cch * 1024),
                16, 0, 0);
        }
        __syncthreads();
        const int rowA = wr * 32 + lo, rowB = wc * 32 + lo;
        #pragma unroll
        for (int s = 0; s < 4; ++s) {
            const int ka = (rowA * 128 + s * 32 + hi * 16) ^ ((rowA & 7) << 4);
            const int kb = (rowB * 128 + s * 32 + hi * 16) ^ ((rowB & 7) << 4);
            bf16x8 af = *(const bf16x8*)((const char*)As + ka);
            bf16x8 bf = *(const bf16x8*)((const char*)Bs + kb);
            acc = mfma32(af, bf, acc);
        }
        __syncthreads();
    }

    const int c = c0 + wc * 32 + lo;
    const float bv = g.bias[mat][c];
    if (MODE == 0) {
        const float sc = g.scale[mat];
        const int h = c >> 6, dd = c & 63;
        bf16_t* out = (bf16_t*)outp + (size_t)mat * PROJ_ELEMS;
        #pragma unroll
        for (int r = 0; r < 16; ++r) {
            int row = r0 + wr * 32 + (r & 3) + 8 * (r >> 2) + 4 * hi;
            int bb = (row >= N_) ? 1 : 0;
            int n = row - bb * N_;
            out[(((size_t)(bb * H_ + h)) * N_ + n) * DH_ + dd] = (bf16_t)((acc[r] + bv) * sc);
        }
    } else {
        float* out = (float*)outp;
        #pragma unroll
        for (int r = 0; r < 16; ++r) {
            int row = r0 + wr * 32 + (r & 3) + 8 * (r >> 2) + 4 * hi;
            out[(size_t)row * DIM_ + c] = acc[r] + bv;
        }
    }
}

// ---------------- fused third-order attention ----------------
// grid (48, 8) x 512 thr: 2 independent bh-groups of 4 waves per block.
// Group g = wid>>2 handles bh = blockIdx.y*2 + g; wave-in-group = wid&3 owns
// i = blockIdx.x*4 + (wid&3). L fragments read from global (L2-hot).
// LDS = 2 x V^T (64x200) = 51.2KB -> up to 3 blocks/CU LDS-wise.
// LAUNCH-BOUNDS LESSON (r5/r6): on this compiler the 2nd arg acts as min
// WORKGROUPS/CU; VGPR cap = 2048/(arg*8 waves). (512,6)->40 VGPR, (512,4)->64
// VGPR: both spill catastrophically (natural body needs ~76-100).
// (512,2) -> cap 128 VGPR >= natural -> no spills.
__global__ __launch_bounds__(512, 2) void attn_kernel(
    const bf16_t* __restrict__ Qg, const bf16_t* __restrict__ Kg,
    const bf16_t* __restrict__ Lg, const bf16_t* __restrict__ Vg,
    bf16_t* __restrict__ Xout)
{
    __shared__ __attribute__((aligned(16))) bf16_t VTlds2[2][64 * 200];  // [g][d][k] pitch 200

    const int tid = threadIdx.x, wid = tid >> 6, lane = tid & 63;
    const int lo = lane & 31, hi = lane >> 5;

    // ---- stage V^T for both groups ----
    for (int idx = tid; idx < 3072; idx += 512) {
        int g = idx / 1536, i2 = idx - g * 1536;
        int dc = i2 / 192, j = i2 - dc * 192;
        const size_t vbase = (size_t)(blockIdx.y * 2 + g) * (N_ * DH_);
        bf16x8 v = *(const bf16x8*)(Vg + vbase + (size_t)j * 64 + dc * 8);
        #pragma unroll
        for (int u = 0; u < 8; ++u)
            VTlds2[g][(dc * 8 + u) * 200 + j] = v[u];
    }
    __syncthreads();

    const int grp = wid >> 2;
    const int bh = blockIdx.y * 2 + grp;
    const size_t base = (size_t)bh * (N_ * DH_);
    const bf16_t* VTlds = VTlds2[grp];

    const int i = blockIdx.x * 4 + (wid & 3);
    const bf16_t* qp = Qg + base + (size_t)i * 64;
    bf16x8 qb[4];
    #pragma unroll
    for (int s = 0; s < 4; ++s) qb[s] = *(const bf16x8*)(qp + s * 16 + hi * 8);

    float xacc0 = 0.f, xacc1 = 0.f;
    float Zp[4] = {0.f, 0.f, 0.f, 0.f};

    for (int jb = 0; jb < 6; ++jb) {
        // B-frag for S^T: (q .* K)[j = jb*32+lo][d], from global (L2-hot)
        bf16x8 bq[4];
        const bf16_t* kp = Kg + base + (size_t)(jb * 32 + lo) * 64;
        #pragma unroll
        for (int s = 0; s < 4; ++s) {
            bf16x8 kv = *(const bf16x8*)(kp + s * 16 + hi * 8);
            bf16x8 t;
            #pragma unroll
            for (int u = 0; u < 8; ++u) t[u] = (bf16_t)((float)kv[u] * (float)qb[s][u]);
            bq[s] = t;
        }

        f32x16 Tc0 = {}, Tc1 = {};
        #pragma unroll
        for (int kh = 0; kh < 2; ++kh) {
            // S^T[k = kh*96 + kt*32 + rows][j = jb*32 + lo], K-dim d = 64
            f32x16 Sc[3];
            #pragma unroll
            for (int kt = 0; kt < 3; ++kt) {
                f32x16 a = {};
                const bf16_t* lrow = Lg + base + (size_t)(kh * 96 + kt * 32 + lo) * 64;
                #pragma unroll
                for (int s = 0; s < 4; ++s) {
                    bf16x8 lf = *(const bf16x8*)(lrow + s * 16 + hi * 8);
                    a = mfma32(lf, bq[s], a);
                }
                Sc[kt] = a;
            }
            #pragma unroll
            for (int kt = 0; kt < 3; ++kt) {
                float e[16];
                #pragma unroll
                for (int r = 0; r < 16; ++r) {
                    e[r] = __builtin_amdgcn_exp2f(Sc[kt][r]);
                    Zp[r & 3] += e[r];
                }
                #pragma unroll
                for (int sg = 0; sg < 2; ++sg) {
                    unsigned int x0 = pack_bf16(e[8*sg+0], e[8*sg+1]);
                    unsigned int x1 = pack_bf16(e[8*sg+2], e[8*sg+3]);
                    unsigned int y0 = pack_bf16(e[8*sg+4], e[8*sg+5]);
                    unsigned int y1 = pack_bf16(e[8*sg+6], e[8*sg+7]);
                    asm volatile("v_permlane32_swap_b32 %0, %1\n\t"
                                 "v_permlane32_swap_b32 %2, %3"
                                 : "+v"(x0), "+v"(y0), "+v"(x1), "+v"(y1));
                    U4 uf; uf.u[0] = x0; uf.u[1] = x1; uf.u[2] = y0; uf.u[3] = y1;
                    const int tg = kh * 6 + kt * 2 + sg;     // k-slice 0..11
                    bf16x8 vf0 = *(const bf16x8*)&VTlds[(0 * 32 + lo) * 200 + tg * 16 + hi * 8];
                    Tc0 = mfma32(uf.v, vf0, Tc0);
                    bf16x8 vf1 = *(const bf16x8*)&VTlds[(1 * 32 + lo) * 200 + tg * 16 + hi * 8];
                    Tc1 = mfma32(uf.v, vf1, Tc1);
                }
            }
        }
        // x[d] += v[j,d] * T[j,d] over this strip's 32 j
        #pragma unroll
        for (int m = 0; m < 4; ++m) {
            const int jj = jb * 32 + m * 8 + 4 * hi;
            ushort4 v0 = *(const ushort4*)&VTlds[(0 * 32 + lo) * 200 + jj];
            ushort4 v1 = *(const ushort4*)&VTlds[(1 * 32 + lo) * 200 + jj];
            xacc0 += Tc0[m*4+0]*bfbits(v0.x) + Tc0[m*4+1]*bfbits(v0.y)
                   + Tc0[m*4+2]*bfbits(v0.z) + Tc0[m*4+3]*bfbits(v0.w);
            xacc1 += Tc1[m*4+0]*bfbits(v1.x) + Tc1[m*4+1]*bfbits(v1.y)
                   + Tc1[m*4+2]*bfbits(v1.z) + Tc1[m*4+3]*bfbits(v1.w);
        }
    }

    float Z = (Zp[0] + Zp[1]) + (Zp[2] + Zp[3]);
    Z += __shfl_xor(Z, 1);
    Z += __shfl_xor(Z, 2);
    Z += __shfl_xor(Z, 4);
    Z += __shfl_xor(Z, 8);
    Z += __shfl_xor(Z, 16);
    Z += __shfl_xor(Z, 32);
    xacc0 += __shfl_xor(xacc0, 32);
    xacc1 += __shfl_xor(xacc1, 32);
    const float invZ = 1.0f / Z;

    if (hi == 0) {
        const int b = bh >> 3, h = bh & 7;
        bf16_t* op = Xout + ((size_t)(b * N_ + i) * DIM_) + h * 64;
        op[lo]      = (bf16_t)(xacc0 * invZ);
        op[32 + lo] = (bf16_t)(xacc1 * invZ);
    }
}

extern "C" void kernel_launch(void* const* d_in, const int* in_sizes, int n_in,
                              void* d_out, int out_size, void* d_ws, size_t ws_size,
                              hipStream_t stream) {
    (void)in_sizes; (void)n_in; (void)out_size; (void)ws_size;
    const float* queries = (const float*)d_in[0];
    const float* keys    = (const float*)d_in[1];
    const float* values  = (const float*)d_in[2];
    const float* Wq = (const float*)d_in[3];
    const float* bq = (const float*)d_in[4];
    const float* Wk = (const float*)d_in[5];
    const float* bk = (const float*)d_in[6];
    const float* Wl = (const float*)d_in[7];
    const float* bl = (const float*)d_in[8];
    const float* Wv = (const float*)d_in[9];
    const float* bv = (const float*)d_in[10];
    const float* Wp = (const float*)d_in[11];
    const float* bp = (const float*)d_in[12];

    bf16_t* Abf = (bf16_t*)d_ws;
    bf16_t* Wbf = Abf + 3 * (size_t)A_ELEMS;
    bf16_t* Pw  = Wbf + 5 * (size_t)W_ELEMS;
    bf16_t* Xw  = Pw  + 4 * (size_t)PROJ_ELEMS;

    CArgs ca;
    ca.src[0] = queries; ca.dst[0] = Abf;               ca.n[0] = A_ELEMS;
    ca.src[1] = keys;    ca.dst[1] = Abf + A_ELEMS;     ca.n[1] = A_ELEMS;
    ca.src[2] = values;  ca.dst[2] = Abf + 2*A_ELEMS;   ca.n[2] = A_ELEMS;
    ca.src[3] = Wq;      ca.dst[3] = Wbf;               ca.n[3] = W_ELEMS;
    ca.src[4] = Wk;      ca.dst[4] = Wbf + W_ELEMS;     ca.n[4] = W_ELEMS;
    ca.src[5] = Wl;      ca.dst[5] = Wbf + 2*W_ELEMS;   ca.n[5] = W_ELEMS;
    ca.src[6] = Wv;      ca.dst[6] = Wbf + 3*W_ELEMS;   ca.n[6] = W_ELEMS;
    ca.src[7] = Wp;      ca.dst[7] = Wbf + 4*W_ELEMS;   ca.n[7] = W_ELEMS;
    cvt_kernel<<<dim3(256, 8), 256, 0, stream>>>(ca);

    GArgs pa;
    pa.A[0] = Abf;             pa.Bm[0] = Wbf;             pa.bias[0] = bq; pa.scale[0] = 0.125f * 1.44269504f;
    pa.A[1] = Abf + A_ELEMS;   pa.Bm[1] = Wbf + W_ELEMS;   pa.bias[1] = bk; pa.scale[1] = 1.0f;
    pa.A[2] = Abf + A_ELEMS;   pa.Bm[2] = Wbf + 2*W_ELEMS; pa.bias[2] = bl; pa.scale[2] = 1.0f;
    pa.A[3] = Abf + 2*A_ELEMS; pa.Bm[3] = Wbf + 3*W_ELEMS; pa.bias[3] = bv; pa.scale[3] = 1.0f;
    gemm64_kernel<0><<<dim3(48, 4), 256, 0, stream>>>(pa, (void*)Pw);

    attn_kernel<<<dim3(48, 8), 512, 0, stream>>>(
        Pw, Pw + PROJ_ELEMS, Pw + 2 * (size_t)PROJ_ELEMS, Pw + 3 * (size_t)PROJ_ELEMS, Xw);

    GArgs fa;
    fa.A[0] = Xw; fa.Bm[0] = Wbf + 4*W_ELEMS; fa.bias[0] = bp; fa.scale[0] = 1.0f;
    fa.A[1] = fa.A[0]; fa.Bm[1] = fa.Bm[0]; fa.bias[1] = fa.bias[0]; fa.scale[1] = 1.0f;
    fa.A[2] = fa.A[0]; fa.Bm[2] = fa.Bm[0]; fa.bias[2] = fa.bias[0]; fa.scale[2] = 1.0f;
    fa.A[3] = fa.A[0]; fa.Bm[3] = fa.Bm[0]; fa.bias[3] = fa.bias[0]; fa.scale[3] = 1.0f;
    gemm64_kernel<1><<<dim3(48, 1), 256, 0, stream>>>(fa, d_out);
}